// Round 3
// baseline (423.550 us; speedup 1.0000x reference)
//
#include <hip/hip_runtime.h>
#include <hip/hip_bf16.h>
#include <stdint.h>

// FusedLinearCrossEntropyLoss on MI355X (gfx950)
// loss = mean_i( logsumexp_j(x_i . w_j + b_j) - (x_i . w_t(i) + b_t(i)) )
//
// R8: 8-WAVE 256x256 TILE, 4-PHASE SCHEDULE (m201 port, fp8 MX).
//     R7's 2-barrier-per-K-step loop hit the structural 2-phase stall
//     (kg period ~3400 cy vs 1104 cy of matrix work -> 32% MfmaUtil; m233).
//     Per the regime gate (m228d/m230/m232) the phase-split needs 8-wave
//     blocks. New geometry: 256x256 tile, 512 thr (2M x 4N waves), per-wave
//     128x64 = 4x2 MFMAs of 32x32x64 fp8. 3 LDS buffers x 32 KB (A 16 + B 16)
//     + 4 KB rowsum = 100 KB, 1 block/CU. Prefetch depth 2 (g+2), counted
//     s_waitcnt vmcnt(4) once per kg (never 0 in steady state). Per kg,
//     4 phases: {ds_read frag subtile | 1 global_load_lds segment ->
//     s_barrier -> setprio(1) -> 2 MFMA -> setprio(0) -> s_barrier}.
//     XCD swizzle bijective (2000 blocks % 8 == 0).
//
// Chunk layout (unchanged; tile-size-agnostic): chunk c = R*16 + g
// (R = 32-row block, g = 64-wide k group). Within chunk: half h in {0,1},
// lane l in 0..63, byte j in 0..15:
//   data[c*2048 + h*1024 + l*16 + j] = M[R*32 + (l&31)][g*64 + (l>>5)*32 + h*16 + j]

typedef float f16v __attribute__((ext_vector_type(16)));
typedef int v8i __attribute__((ext_vector_type(8)));

__device__ __forceinline__ unsigned pk_fp8(float4 v) {
  int w = 0;
  w = __builtin_amdgcn_cvt_pk_fp8_f32(v.x, v.y, w, false);  // bytes 0,1
  w = __builtin_amdgcn_cvt_pk_fp8_f32(v.z, v.w, w, true);   // bytes 2,3
  return (unsigned)w;
}

// fp32 [N x 1024] -> fp8 fragment-swizzled chunks. One thread = 16 out bytes.
__global__ __launch_bounds__(256) void cast_swz_k(const float* __restrict__ in,
                                                  uint4* __restrict__ out,
                                                  long n16) {
  long t = (long)blockIdx.x * blockDim.x + threadIdx.x;
  long stride = (long)gridDim.x * blockDim.x;
  for (; t < n16; t += stride) {
    long o = t * 16;
    int c = (int)(o >> 11);
    int rem = (int)(o & 2047);
    int h = rem >> 10;
    int lam = (rem >> 4) & 63;
    int row = (c >> 4) * 32 + (lam & 31);
    int k = (c & 15) * 64 + (lam >> 5) * 32 + h * 16;
    const float4* src = (const float4*)(in + (long)row * 1024 + k);
    uint4 oo;
    oo.x = pk_fp8(src[0]); oo.y = pk_fp8(src[1]);
    oo.z = pk_fp8(src[2]); oo.w = pk_fp8(src[3]);
    out[t] = oo;
  }
}

// One block per row: x_y[row] = x[row] . W[safe_t] + bias[safe_t]  (fp32, exact)
__global__ __launch_bounds__(256) void xy_k(const float* __restrict__ x,
                                            const float* __restrict__ w,
                                            const float* __restrict__ bias,
                                            const int* __restrict__ tgt,
                                            float* __restrict__ xy, int H, int V) {
  int row = blockIdx.x;
  int t = tgt[row];
  int st = min(max(t, 0), V - 1);
  const float4* xr = (const float4*)(x + (long)row * H);
  const float4* wr = (const float4*)(w + (long)st * H);
  float s = 0.f;
  int n4 = H >> 2;
  for (int i = threadIdx.x; i < n4; i += 256) {
    float4 a = xr[i], b = wr[i];
    s += a.x * b.x + a.y * b.y + a.z * b.z + a.w * b.w;
  }
  for (int off = 32; off; off >>= 1) s += __shfl_down(s, off, 64);
  __shared__ float sm[4];
  if ((threadIdx.x & 63) == 0) sm[threadIdx.x >> 6] = s;
  __syncthreads();
  if (threadIdx.x == 0) xy[row] = sm[0] + sm[1] + sm[2] + sm[3] + bias[st];
}

// 256x256 block tile, 8 waves in 2x4; each wave 128x64 via 4x2 of 32x32x64.
// LDS: 3 k-group buffers of 32 KB (A chunks 0..7 @ i*2048, B chunks @ 16384+j*2048)
// + rowsum. Epilogue: partials[by][row] = sum over this 256-col panel of
// exp(logit + bias).
#define LDS_KG 32768

__global__ __launch_bounds__(512, 2)
void gemm_sumexp(const char* __restrict__ Xf, const char* __restrict__ Wf,
                 const float* __restrict__ bias, float* __restrict__ partials,
                 int H, int BT) {
  __shared__ char lds[3 * LDS_KG];       // 96 KB
  __shared__ float rowsum[4][256];       // 4 KB

  const int tid = threadIdx.x;
  const int w = tid >> 6, lane = tid & 63;
  const int wr = w >> 2, wc = w & 3;     // 2 x 4 wave grid
  const int l32 = lane & 31, kh = lane >> 5;

  // Bijective XCD-aware swizzle (nwg = 2000, divisible by 8).
  const int nbx = gridDim.x;
  const int nwg = nbx * gridDim.y;
  const int id = blockIdx.y * nbx + blockIdx.x;
  const int swz = ((nwg & 7) == 0) ? ((id & 7) * (nwg >> 3) + (id >> 3)) : id;
  const int bx = swz % nbx;
  const int by = swz / nbx;
  const int m0 = bx * 256, n0 = by * 256;

  // Staging: 32 segments of 1 KB per k-group (A 16, B 16); 4 per wave,
  // one issued per phase. gl_lds dest = wave-uniform base + lane*16.
  const char* segsrc[4];
  int segdst[4];
#pragma unroll
  for (int r = 0; r < 4; ++r) {
    const int s = w * 4 + r;
    if (s < 16) {
      long base = (long)(bx * 8 + (s >> 1)) * 32768 + (long)(s & 1) * 1024;
      segsrc[r] = Xf + base + lane * 16;
    } else {
      long base = (long)(by * 8 + ((s - 16) >> 1)) * 32768 + (long)((s - 16) & 1) * 1024;
      segsrc[r] = Wf + base + lane * 16;
    }
    segdst[r] = s * 1024;
  }

  auto STAGE1 = [&](int g, int bo, int r) {
    __builtin_amdgcn_global_load_lds(
        (const __attribute__((address_space(1))) void*)(segsrc[r] + (long)g * 2048),
        (__attribute__((address_space(3))) void*)(lds + bo + segdst[r]),
        16, 0, 0);
  };

  f16v acc[4][2];
#pragma unroll
  for (int mi = 0; mi < 4; mi++)
#pragma unroll
    for (int ni = 0; ni < 2; ni++)
#pragma unroll
      for (int r = 0; r < 16; r++) acc[mi][ni][r] = 0.f;

  const int nG = H >> 6;  // 16 k-groups of 64 (requires nG >= 3)

  // Prologue: fill buffers 0,1; wait for buffer 0 only (counted).
  {
#pragma unroll
    for (int r = 0; r < 4; ++r) STAGE1(0, 0, r);
#pragma unroll
    for (int r = 0; r < 4; ++r) STAGE1(1, LDS_KG, r);
  }
  asm volatile("s_waitcnt vmcnt(4)" ::: "memory");
  __builtin_amdgcn_s_barrier();

  int bo = 0;  // LDS buffer holding k-group g
  for (int g = 0; g < nG; ++g) {
    const char* A = lds + bo;
    const char* B = lds + bo + 16384;
    int bo2 = bo + 2 * LDS_KG;
    if (bo2 >= 3 * LDS_KG) bo2 -= 3 * LDS_KG;  // buffer for g+2
    const bool pf = (g + 2 < nG);

    v8i a0, a1, a2, a3, b0, b1;
#define LDFRAG(dst, base, chunk)                                   \
    {                                                              \
      const char* p = (base) + (chunk) * 2048 + lane * 16;         \
      int4 lo = *(const int4*)(p);                                 \
      int4 hi = *(const int4*)(p + 1024);                          \
      v8i t;                                                       \
      t[0] = lo.x; t[1] = lo.y; t[2] = lo.z; t[3] = lo.w;          \
      t[4] = hi.x; t[5] = hi.y; t[6] = hi.z; t[7] = hi.w;          \
      dst = t;                                                     \
    }

    // ---- phase 0: read A0,A1,B0 ; stage seg 0 ; mfma (mi0,mi1) x ni0 ----
    LDFRAG(a0, A, (wr * 4 + 0));
    LDFRAG(a1, A, (wr * 4 + 1));
    LDFRAG(b0, B, (wc * 2 + 0));
    if (pf) STAGE1(g + 2, bo2, 0);
    __builtin_amdgcn_s_barrier();
    __builtin_amdgcn_s_setprio(1);
    acc[0][0] = __builtin_amdgcn_mfma_scale_f32_32x32x64_f8f6f4(
        a0, b0, acc[0][0], 0, 0, 0, 127, 0, 127);
    acc[1][0] = __builtin_amdgcn_mfma_scale_f32_32x32x64_f8f6f4(
        a1, b0, acc[1][0], 0, 0, 0, 127, 0, 127);
    __builtin_amdgcn_s_setprio(0);
    __builtin_amdgcn_s_barrier();

    // ---- phase 1: read A2,A3,B1 ; stage seg 1 ; mfma (mi2,mi3) x ni0 ----
    LDFRAG(a2, A, (wr * 4 + 2));
    LDFRAG(a3, A, (wr * 4 + 3));
    LDFRAG(b1, B, (wc * 2 + 1));
    if (pf) STAGE1(g + 2, bo2, 1);
    __builtin_amdgcn_s_barrier();
    __builtin_amdgcn_s_setprio(1);
    acc[2][0] = __builtin_amdgcn_mfma_scale_f32_32x32x64_f8f6f4(
        a2, b0, acc[2][0], 0, 0, 0, 127, 0, 127);
    acc[3][0] = __builtin_amdgcn_mfma_scale_f32_32x32x64_f8f6f4(
        a3, b0, acc[3][0], 0, 0, 0, 127, 0, 127);
    __builtin_amdgcn_s_setprio(0);
    __builtin_amdgcn_s_barrier();

    // ---- phase 2: stage seg 2 ; mfma (mi0,mi1) x ni1 ----
    if (pf) STAGE1(g + 2, bo2, 2);
    __builtin_amdgcn_s_barrier();
    __builtin_amdgcn_s_setprio(1);
    acc[0][1] = __builtin_amdgcn_mfma_scale_f32_32x32x64_f8f6f4(
        a0, b1, acc[0][1], 0, 0, 0, 127, 0, 127);
    acc[1][1] = __builtin_amdgcn_mfma_scale_f32_32x32x64_f8f6f4(
        a1, b1, acc[1][1], 0, 0, 0, 127, 0, 127);
    __builtin_amdgcn_s_setprio(0);
    __builtin_amdgcn_s_barrier();

    // ---- phase 3: stage seg 3 ; mfma (mi2,mi3) x ni1 ; kg-boundary vmcnt ----
    if (pf) STAGE1(g + 2, bo2, 3);
    __builtin_amdgcn_s_barrier();
    __builtin_amdgcn_s_setprio(1);
    acc[2][1] = __builtin_amdgcn_mfma_scale_f32_32x32x64_f8f6f4(
        a2, b1, acc[2][1], 0, 0, 0, 127, 0, 127);
    acc[3][1] = __builtin_amdgcn_mfma_scale_f32_32x32x64_f8f6f4(
        a3, b1, acc[3][1], 0, 0, 0, 127, 0, 127);
    __builtin_amdgcn_s_setprio(0);
    // ensure (g+1)'s 4 loads landed; (g+2)'s 4 stay in flight (counted).
    if (pf) {
      asm volatile("s_waitcnt vmcnt(4)" ::: "memory");
    } else if (g + 1 < nG) {
      asm volatile("s_waitcnt vmcnt(0)" ::: "memory");
    }
    __builtin_amdgcn_s_barrier();

    bo += LDS_KG;
    if (bo >= 3 * LDS_KG) bo -= 3 * LDS_KG;
#undef LDFRAG
  }

  // ---- epilogue: per-row sum of exp(logit + bias) ----
  // C/D 32x32 layout: col = lane&31, row = (reg&3) + 8*(reg>>2) + 4*(lane>>5)
  float bv[2];
  bv[0] = bias[n0 + wc * 64 + l32];
  bv[1] = bias[n0 + wc * 64 + 32 + l32];

#pragma unroll
  for (int mi = 0; mi < 4; mi++) {
    float p[16];
#pragma unroll
    for (int r = 0; r < 16; r++) p[r] = 0.f;
#pragma unroll
    for (int ni = 0; ni < 2; ni++)
#pragma unroll
      for (int r = 0; r < 16; r++) p[r] += __expf(acc[mi][ni][r] + bv[ni]);
    // reduce across the 32 columns (lanes within each 32-group)
#pragma unroll
    for (int off = 1; off < 32; off <<= 1)
#pragma unroll
      for (int r = 0; r < 16; r++) p[r] += __shfl_xor(p[r], off, 32);
    if (l32 == 0) {
#pragma unroll
      for (int r = 0; r < 16; r++)
        rowsum[wc][wr * 128 + mi * 32 + (r & 3) + 8 * (r >> 2) + 4 * kh] = p[r];
    }
  }
  __syncthreads();
  if (tid < 256)
    partials[(long)by * BT + m0 + tid] =
        rowsum[0][tid] + rowsum[1][tid] + rowsum[2][tid] + rowsum[3][tid];
}

// per-row: lse - x_y ; 4 threads per row for b-parallelism, 64 rows/block
__global__ __launch_bounds__(256)
void row_reduce(const float* __restrict__ partials, const float* __restrict__ xy,
                const int* __restrict__ tgt, float* __restrict__ bsum,
                float* __restrict__ bcnt, int BT, int nCB) {
  const int row = blockIdx.x * 64 + (threadIdx.x >> 2);
  const int q = threadIdx.x & 3;
  float S = 0.f;
  for (int b = q; b < nCB; b += 4) S += partials[(long)b * BT + row];
  S += __shfl_xor(S, 1, 64);
  S += __shfl_xor(S, 2, 64);
  float pr = 0.f, c = 0.f;
  if (q == 0) {
    int t = tgt[row];
    if (t != -100) { pr = logf(S) - xy[row]; c = 1.f; }
  }
  for (int off = 32; off; off >>= 1) {
    pr += __shfl_down(pr, off, 64);
    c += __shfl_down(c, off, 64);
  }
  __shared__ float sp[4], sc[4];
  if ((threadIdx.x & 63) == 0) {
    sp[threadIdx.x >> 6] = pr;
    sc[threadIdx.x >> 6] = c;
  }
  __syncthreads();
  if (threadIdx.x == 0) {
    bsum[blockIdx.x] = sp[0] + sp[1] + sp[2] + sp[3];
    bcnt[blockIdx.x] = sc[0] + sc[1] + sc[2] + sc[3];
  }
}

__global__ void finalize(const float* __restrict__ bsum, const float* __restrict__ bcnt,
                         float* __restrict__ out, int nb) {
  float s = 0.f, c = 0.f;
  for (int i = threadIdx.x; i < nb; i += 64) { s += bsum[i]; c += bcnt[i]; }
  for (int off = 32; off; off >>= 1) {
    s += __shfl_down(s, off, 64);
    c += __shfl_down(c, off, 64);
  }
  if (threadIdx.x == 0) out[0] = s / c;
}

extern "C" void kernel_launch(void* const* d_in, const int* in_sizes, int n_in,
                              void* d_out, int out_size, void* d_ws, size_t ws_size,
                              hipStream_t stream) {
  const float* x = (const float*)d_in[0];
  const int* tgt = (const int*)d_in[1];
  const float* w = (const float*)d_in[2];
  const float* bias = (const float*)d_in[3];
  float* out = (float*)d_out;

  const int BT = in_sizes[1];            // 4096
  const int V = in_sizes[3];             // 32000
  const int H = in_sizes[0] / BT;        // 1024
  const int nCB = V / 256;               // 125 column panels

  char* ws = (char*)d_ws;
  const long wb_bytes = (long)V * H;     // fp8: 1 B/elem
  const long xb_bytes = (long)BT * H;
  char* Wf = ws;
  char* Xf = ws + wb_bytes;
  float* partials = (float*)(ws + wb_bytes + xb_bytes);
  float* xy = partials + (long)nCB * BT;
  float* bsum = xy + BT;
  float* bcnt = bsum + (BT / 64);

  cast_swz_k<<<8192, 256, 0, stream>>>(w, (uint4*)Wf, (long)V * H / 16);
  cast_swz_k<<<1024, 256, 0, stream>>>(x, (uint4*)Xf, (long)BT * H / 16);
  xy_k<<<BT, 256, 0, stream>>>(x, w, bias, tgt, xy, H, V);
  dim3 grid(BT / 256, nCB);
  gemm_sumexp<<<grid, 512, 0, stream>>>(Xf, Wf, bias, partials, H, BT);
  row_reduce<<<BT / 64, 256, 0, stream>>>(partials, xy, tgt, bsum, bcnt, BT, nCB);
  finalize<<<1, 64, 0, stream>>>(bsum, bcnt, out, BT / 64);
}